// Round 3
// baseline (161.326 us; speedup 1.0000x reference)
//
#include <hip/hip_runtime.h>
#include <math.h>

typedef __attribute__((ext_vector_type(8))) short s16x8;
typedef __attribute__((ext_vector_type(4))) float f32x4;

#define CCH 128
#define BSZ 32

// fp32 -> bf16 round-to-nearest-even
static __device__ inline unsigned short f2bf(float f) {
    unsigned u = __float_as_uint(f);
    unsigned r = (u + 0x7FFFu + ((u >> 16) & 1u)) >> 16;
    return (unsigned short)r;
}

// ---------------- Kernel A: global average pool ----------------
__global__ __launch_bounds__(256) void pool_kernel(const float* __restrict__ x,
                                                   float* __restrict__ pooled) {
    int blk = blockIdx.x;                 // b*C + c
    const float4* x4 = (const float4*)(x + (size_t)blk * 4096);
    int t = threadIdx.x;
    float s = 0.f;
#pragma unroll
    for (int j = 0; j < 4; ++j) {
        float4 v = x4[j * 256 + t];
        s += v.x + v.y + v.z + v.w;
    }
#pragma unroll
    for (int off = 32; off; off >>= 1) s += __shfl_xor(s, off, 64);
    __shared__ float red[4];
    if ((t & 63) == 0) red[t >> 6] = s;
    __syncthreads();
    if (t == 0) {
        float tot = red[0] + red[1] + red[2] + red[3];
        pooled[blk] = tot * (1.0f / 4096.0f);
    }
}

// ---------------- Kernel B: routing coefficients ----------------
__global__ __launch_bounds__(128) void coeff_kernel(const float* __restrict__ pooled,
                                                    const float* __restrict__ fc_w,
                                                    const float* __restrict__ fc_b,
                                                    float* __restrict__ coeffs) {
    int t = threadIdx.x;
    int b = t >> 2, k = t & 3;
    const float4* p4 = (const float4*)(pooled + b * CCH);
    const float4* w4 = (const float4*)(fc_w + k * CCH);
    float dot = fc_b[k];
#pragma unroll
    for (int j = 0; j < 32; ++j) {
        float4 a = p4[j], w = w4[j];
        dot += a.x * w.x + a.y * w.y + a.z * w.z + a.w * w.w;
    }
    float s = 1.0f / (1.0f + expf(-dot));
    float m = s;
    m = fmaxf(m, __shfl_xor(m, 1, 64));
    m = fmaxf(m, __shfl_xor(m, 2, 64));
    float e = expf(s - m);
    float sum = e;
    sum += __shfl_xor(sum, 1, 64);
    sum += __shfl_xor(sum, 2, 64);
    coeffs[t] = e / sum;
}

// ---------------- Kernel W: mix weights -> bf16, padded layout ----------------
// wmix[b][cc(4)][dy(3)][dx(3)][co(128)][ci 32 padded to 40] bf16
__global__ __launch_bounds__(256) void mix_kernel(const float* __restrict__ kernels,
                                                  const float* __restrict__ coeffs,
                                                  unsigned short* __restrict__ wmix) {
    int idx = blockIdx.x * 256 + threadIdx.x;   // < 589824
    int c8 = idx & 3;
    int r = idx >> 2;
    int co = r & 127; r >>= 7;
    int dx = r % 3; int r2 = r / 3;
    int dy = r2 % 3; r2 /= 3;
    int cc = r2 & 3; int b = r2 >> 2;

    float cf0 = coeffs[b * 4 + 0];
    float cf1 = coeffs[b * 4 + 1];
    float cf2 = coeffs[b * 4 + 2];
    float cf3 = coeffs[b * 4 + 3];

    const int KSTR = 128 * 128 * 9;
    unsigned short vals[8];
#pragma unroll
    for (int i = 0; i < 8; ++i) {
        int ci = cc * 32 + c8 * 8 + i;
        const float* kp = kernels + ((size_t)co * CCH + ci) * 9 + dy * 3 + dx;
        float s = cf0 * kp[0] + cf1 * kp[KSTR] + cf2 * kp[2 * KSTR] + cf3 * kp[3 * KSTR];
        vals[i] = f2bf(s);
    }
    size_t o = ((size_t)((((b * 4 + cc) * 3 + dy) * 3 + dx) * 128 + co)) * 40 + c8 * 8;
    *(s16x8*)&wmix[o] = *(const s16x8*)vals;
}

// ---------------- Kernel C: MFMA implicit-GEMM dynamic conv ----------------
// Same geometry as round 2 (128co x 4rows x 64cols per block, 12 (cc,dy) phases)
// + T14 register-prefetch of wl (every phase) and x (cc boundaries) so the
// global->LDS staging latency hides under the previous phase's compute.
__global__ __launch_bounds__(512, 4) void conv_kernel(const float* __restrict__ x,
                                                      const unsigned short* __restrict__ wmix,
                                                      float* __restrict__ out) {
    __shared__ unsigned short xs[6 * 66 * 40];   // 31680 B
    __shared__ unsigned short wl[1920 * 8];      // 30720 B

    int blk = blockIdx.x;
    int ytile = blk & 15, b = blk >> 4;
    int y0 = ytile * 4;
    int t = threadIdx.x;
    int l = t & 63, w = t >> 6;
    int wr = w >> 2, wc = w & 3;
    int l15 = l & 15, g = l >> 4;

    const unsigned short* wb = wmix + (size_t)b * 184320;

    // halo columns (col 0 and 65) zeroed once
    if (t < 240) {
        int cpart = t % 20;
        int colsel = (t / 20) & 1;
        int row = t / 40;
        int col = colsel * 65;
        *(unsigned*)&xs[(row * 66 + col) * 40 + cpart * 2] = 0u;
    }

    f32x4 acc[4][4] = {};

    // ---- prologue: stage x(cc=0) and wl(phase 0) directly ----
    {
#pragma unroll
        for (int i = 0; i < 12; ++i) {
            int it = w + i * 8;
            int row = it >> 4, colhi = (it >> 2) & 3, cphi = it & 3;
            int cp = cphi * 4 + g;
            int gx = colhi * 16 + l15;
            int gy = y0 + row - 1;
            float v0 = 0.f, v1 = 0.f;
            if ((unsigned)gy < 64u) {
                const float* xp = x + (((size_t)b * CCH + cp * 2) * 64 + gy) * 64 + gx;
                v0 = xp[0];
                v1 = xp[4096];
            }
            unsigned pk = (unsigned)f2bf(v0) | ((unsigned)f2bf(v1) << 16);
            *(unsigned*)&xs[(row * 66 + gx + 1) * 40 + cp * 2] = pk;
        }
#pragma unroll
        for (int i = 0; i < 4; ++i) {
            int s = t + i * 512;
            if (s < 1920) *(s16x8*)&wl[s * 8] = *(const s16x8*)&wb[(size_t)s * 8];
        }
    }
    __syncthreads();

    // prefetch registers
    s16x8 wlpf[4];
    float xv0[12], xv1[12];

    for (int p = 0; p < 12; ++p) {
        int dy = p - (p / 3) * 3;
        int cc = p / 3;

        // ---- issue prefetch loads for phase p+1 (overlap with compute) ----
        if (p < 11) {
            int pn = p + 1;
            const unsigned short* wsrc = wb + (size_t)pn * 15360;  // (cc*3+dy) contiguous
#pragma unroll
            for (int i = 0; i < 4; ++i) {
                int s = t + i * 512;
                if (s < 1920) wlpf[i] = *(const s16x8*)&wsrc[(size_t)s * 8];
            }
            if (dy == 2) {  // cc boundary: prefetch x for cc+1
                int ccn = cc + 1;
#pragma unroll
                for (int i = 0; i < 12; ++i) {
                    int it = w + i * 8;
                    int row = it >> 4, colhi = (it >> 2) & 3, cphi = it & 3;
                    int cp = cphi * 4 + g;
                    int gx = colhi * 16 + l15;
                    int gy = y0 + row - 1;
                    float v0 = 0.f, v1 = 0.f;
                    if ((unsigned)gy < 64u) {
                        const float* xp = x + (((size_t)b * CCH + ccn * 32 + cp * 2) * 64 + gy) * 64 + gx;
                        v0 = xp[0];
                        v1 = xp[4096];
                    }
                    xv0[i] = v0; xv1[i] = v1;
                }
            }
        }

        // ---- compute phase p ----
        int xrow = wc + dy;
#pragma unroll
        for (int dx = 0; dx < 3; ++dx) {
            s16x8 a[4];
#pragma unroll
            for (int mt = 0; mt < 4; ++mt)
                a[mt] = *(const s16x8*)&wl[(dx * 128 + wr * 64 + mt * 16 + l15) * 40 + g * 8];
#pragma unroll
            for (int nt = 0; nt < 4; ++nt) {
                s16x8 bf = *(const s16x8*)&xs[(xrow * 66 + nt * 16 + l15 + dx) * 40 + g * 8];
#pragma unroll
                for (int mt = 0; mt < 4; ++mt)
                    acc[mt][nt] = __builtin_amdgcn_mfma_f32_16x16x32_bf16(
                        a[mt], bf, acc[mt][nt], 0, 0, 0);
            }
        }

        __syncthreads();   // everyone done reading wl/xs of phase p

        // ---- write prefetched data for phase p+1 ----
        if (p < 11) {
#pragma unroll
            for (int i = 0; i < 4; ++i) {
                int s = t + i * 512;
                if (s < 1920) *(s16x8*)&wl[s * 8] = wlpf[i];
            }
            if (dy == 2) {
#pragma unroll
                for (int i = 0; i < 12; ++i) {
                    int it = w + i * 8;
                    int row = it >> 4, colhi = (it >> 2) & 3, cphi = it & 3;
                    int cp = cphi * 4 + g;
                    int gx = colhi * 16 + l15;
                    unsigned pk = (unsigned)f2bf(xv0[i]) | ((unsigned)f2bf(xv1[i]) << 16);
                    *(unsigned*)&xs[(row * 66 + gx + 1) * 40 + cp * 2] = pk;
                }
            }
            __syncthreads();
        }
    }

    // ---- epilogue ----
    int gy_out = y0 + wc;
#pragma unroll
    for (int mt = 0; mt < 4; ++mt) {
#pragma unroll
        for (int nt = 0; nt < 4; ++nt) {
            int gx_out = nt * 16 + l15;
#pragma unroll
            for (int j = 0; j < 4; ++j) {
                int co = wr * 64 + mt * 16 + g * 4 + j;
                out[(((size_t)b * CCH + co) * 64 + gy_out) * 64 + gx_out] = acc[mt][nt][j];
            }
        }
    }
}

extern "C" void kernel_launch(void* const* d_in, const int* in_sizes, int n_in,
                              void* d_out, int out_size, void* d_ws, size_t ws_size,
                              hipStream_t stream) {
    const float* x       = (const float*)d_in[0];
    const float* kernels = (const float*)d_in[1];
    const float* fc_w    = (const float*)d_in[2];
    const float* fc_b    = (const float*)d_in[3];
    float* out = (float*)d_out;

    float* pooled = (float*)d_ws;
    float* coeffs = pooled + BSZ * CCH;
    unsigned short* wmix = (unsigned short*)((char*)d_ws + 32768);

    pool_kernel<<<BSZ * CCH, 256, 0, stream>>>(x, pooled);
    coeff_kernel<<<1, 128, 0, stream>>>(pooled, fc_w, fc_b, coeffs);
    mix_kernel<<<2304, 256, 0, stream>>>(kernels, coeffs, wmix);
    conv_kernel<<<512, 512, 0, stream>>>(x, wmix, out);
}

// Round 4
// 100.457 us; speedup vs baseline: 1.6059x; 1.6059x over previous
//
#include <hip/hip_runtime.h>
#include <math.h>

typedef __attribute__((ext_vector_type(8))) short s16x8;
typedef __attribute__((ext_vector_type(4))) float f32x4;
typedef __attribute__((ext_vector_type(4))) unsigned int u32x4;

#define CCH 128
#define BSZ 32

// fp32 -> bf16 round-to-nearest-even
static __device__ inline unsigned short f2bf(float f) {
    unsigned u = __float_as_uint(f);
    unsigned r = (u + 0x7FFFu + ((u >> 16) & 1u)) >> 16;
    return (unsigned short)r;
}

// ---------------- Kernel A: global average pool ----------------
__global__ __launch_bounds__(256) void pool_kernel(const float* __restrict__ x,
                                                   float* __restrict__ pooled) {
    int blk = blockIdx.x;                 // b*C + c
    const float4* x4 = (const float4*)(x + (size_t)blk * 4096);
    int t = threadIdx.x;
    float s = 0.f;
#pragma unroll
    for (int j = 0; j < 4; ++j) {
        float4 v = x4[j * 256 + t];
        s += v.x + v.y + v.z + v.w;
    }
#pragma unroll
    for (int off = 32; off; off >>= 1) s += __shfl_xor(s, off, 64);
    __shared__ float red[4];
    if ((t & 63) == 0) red[t >> 6] = s;
    __syncthreads();
    if (t == 0) {
        float tot = red[0] + red[1] + red[2] + red[3];
        pooled[blk] = tot * (1.0f / 4096.0f);
    }
}

// ---------------- Kernel W: coeffs (inline) + mix weights -> bf16 ----------------
// wmix[b][cc(4)][dy(3)][dx(3)][co(128)][ci 32 padded to 40] bf16
__global__ __launch_bounds__(256) void mix_kernel(const float* __restrict__ kernels,
                                                  const float* __restrict__ pooled,
                                                  const float* __restrict__ fc_w,
                                                  const float* __restrict__ fc_b,
                                                  unsigned short* __restrict__ wmix) {
    int bid = blockIdx.x;
    bid = (bid & 7) * 288 + (bid >> 3);       // XCD chunk swizzle (2304 = 8*288)
    int idx = bid * 256 + threadIdx.x;        // < 589824
    int c8 = idx & 3;
    int r = idx >> 2;
    int co = r & 127; r >>= 7;
    int dx = r % 3; int r2 = r / 3;
    int dy = r2 % 3; r2 /= 3;
    int cc = r2 & 3; int b = r2 >> 2;

    // ---- routing coefficients, computed redundantly per thread (b uniform per block)
    int bu = __builtin_amdgcn_readfirstlane(b);
    float dot0 = fc_b[0], dot1 = fc_b[1], dot2 = fc_b[2], dot3 = fc_b[3];
    const float4* p4  = (const float4*)(pooled + bu * CCH);
    const float4* w40 = (const float4*)(fc_w);
    const float4* w41 = (const float4*)(fc_w + CCH);
    const float4* w42 = (const float4*)(fc_w + 2 * CCH);
    const float4* w43 = (const float4*)(fc_w + 3 * CCH);
#pragma unroll 8
    for (int j = 0; j < 32; ++j) {
        float4 a = p4[j];
        float4 u;
        u = w40[j]; dot0 += a.x * u.x + a.y * u.y + a.z * u.z + a.w * u.w;
        u = w41[j]; dot1 += a.x * u.x + a.y * u.y + a.z * u.z + a.w * u.w;
        u = w42[j]; dot2 += a.x * u.x + a.y * u.y + a.z * u.z + a.w * u.w;
        u = w43[j]; dot3 += a.x * u.x + a.y * u.y + a.z * u.z + a.w * u.w;
    }
    float s0 = 1.0f / (1.0f + expf(-dot0));
    float s1 = 1.0f / (1.0f + expf(-dot1));
    float s2 = 1.0f / (1.0f + expf(-dot2));
    float s3 = 1.0f / (1.0f + expf(-dot3));
    float m = fmaxf(fmaxf(s0, s1), fmaxf(s2, s3));
    float e0 = expf(s0 - m), e1 = expf(s1 - m), e2 = expf(s2 - m), e3 = expf(s3 - m);
    float inv = 1.0f / (e0 + e1 + e2 + e3);
    float cf0 = e0 * inv, cf1 = e1 * inv, cf2 = e2 * inv, cf3 = e3 * inv;

    // ---- mix
    const int KSTR = 128 * 128 * 9;
    unsigned short vals[8];
#pragma unroll
    for (int i = 0; i < 8; ++i) {
        int ci = cc * 32 + c8 * 8 + i;
        const float* kp = kernels + ((size_t)co * CCH + ci) * 9 + dy * 3 + dx;
        float s = cf0 * kp[0] + cf1 * kp[KSTR] + cf2 * kp[2 * KSTR] + cf3 * kp[3 * KSTR];
        vals[i] = f2bf(s);
    }
    size_t o = ((size_t)((((b * 4 + cc) * 3 + dy) * 3 + dx) * 128 + co)) * 40 + c8 * 8;
    *(s16x8*)&wmix[o] = *(const s16x8*)vals;
}

// ---------------- Kernel C: MFMA implicit-GEMM dynamic conv ----------------
// grid = 256 blocks (32 b x 8 ytiles of 8 rows), 512 threads (8 waves: wr2 x wc4).
// Per block: 128 co x (8 rows x 64 cols). 12 (cc,dy) phases of K=32.
// wl double-buffered in LDS, staged via global_load_lds issued a phase ahead
// (2-phase pipeline); x staged per-cc with reg prefetch under dy=2 compute.
__global__ __launch_bounds__(512, 2) void conv_kernel(const float* __restrict__ x,
                                                      const unsigned short* __restrict__ wmix,
                                                      float* __restrict__ out) {
    extern __shared__ unsigned short smem[];
    unsigned short* xs = smem;            // [10][66][40] = 26400 shorts (52800 B)
    unsigned short* wl = smem + 26400;    // [2][15360]   = 30720 shorts (61440 B)

    int blk = blockIdx.x;
    blk = (blk & 7) * 32 + (blk >> 3);    // XCD chunk swizzle (256 = 8*32)
    int ytile = blk & 7, b = blk >> 3;
    int y0 = ytile * 8;
    int t = threadIdx.x;
    int l = t & 63, w = t >> 6;
    int wr = w >> 2, wc = w & 3;
    int l15 = l & 15, g = l >> 4;

    const unsigned short* wb = wmix + (size_t)b * 184320;

    // zero halo columns (col 0 and 65) for all 10 rows, once
    if (t < 400) {
        int row = t / 40;
        int colsel = (t / 20) & 1;
        int cpart = t % 20;
        *(unsigned*)&xs[(size_t)(row * 66 + colsel * 65) * 40 + cpart * 2] = 0u;
    }

    // ---- issue wl phase-0 loads (async global->LDS, no VGPRs) ----
#pragma unroll
    for (int i = 0; i < 4; ++i) {
        int slot = w + i * 8;
        if (slot < 30) {                   // wave-uniform guard
            size_t s = (size_t)slot * 64 + l;
            __builtin_amdgcn_global_load_lds(
                (const __attribute__((address_space(1))) void*)(wb + s * 8),
                (__attribute__((address_space(3))) void*)(wl + s * 8), 16, 0, 0);
        }
    }

    // ---- stage xs for cc=0 ----
#pragma unroll
    for (int i = 0; i < 5; ++i) {
        int it = w + i * 8;                // 40 slots: row(10) x colhi(4)
        int row = it >> 2, colhi = it & 3;
        int gx = colhi * 16 + l15;
        int gy = y0 + row - 1;
        float v[8];
#pragma unroll
        for (int j = 0; j < 8; ++j) v[j] = 0.f;
        if ((unsigned)gy < 64u) {
            const float* xp = x + (((size_t)b * CCH + g * 8) * 64 + gy) * 64 + gx;
#pragma unroll
            for (int j = 0; j < 8; ++j) v[j] = xp[(size_t)j * 4096];
        }
        unsigned pk[4];
#pragma unroll
        for (int j = 0; j < 4; ++j)
            pk[j] = (unsigned)f2bf(v[2 * j]) | ((unsigned)f2bf(v[2 * j + 1]) << 16);
        *(u32x4*)&xs[(size_t)(row * 66 + gx + 1) * 40 + g * 8] = *(const u32x4*)pk;
    }
    __syncthreads();   // drains vmcnt(0): wl buf0 + xs resident

    f32x4 acc[2][4][4] = {};
    float xv[5][8];

    for (int p = 0; p < 12; ++p) {
        int cc = p / 3;
        int dy = p - cc * 3;
        unsigned short* wcur = wl + (p & 1) * 15360;
        unsigned short* wnxt = wl + ((p + 1) & 1) * 15360;

        if (p < 11) {
            // ---- issue next phase's wl loads into the other buffer ----
            const unsigned short* wsrc = wb + (size_t)(p + 1) * 15360;
#pragma unroll
            for (int i = 0; i < 4; ++i) {
                int slot = w + i * 8;
                if (slot < 30) {
                    size_t s = (size_t)slot * 64 + l;
                    __builtin_amdgcn_global_load_lds(
                        (const __attribute__((address_space(1))) void*)(wsrc + s * 8),
                        (__attribute__((address_space(3))) void*)(wnxt + s * 8), 16, 0, 0);
                }
            }
            if (dy == 2) {
                // ---- prefetch x(cc+1) into regs (consumed after the barrier) ----
#pragma unroll
                for (int i = 0; i < 5; ++i) {
                    int it = w + i * 8;
                    int row = it >> 2, colhi = it & 3;
                    int gx = colhi * 16 + l15;
                    int gy = y0 + row - 1;
#pragma unroll
                    for (int j = 0; j < 8; ++j) xv[i][j] = 0.f;
                    if ((unsigned)gy < 64u) {
                        const float* xp = x + (((size_t)b * CCH + (cc + 1) * 32 + g * 8) * 64 + gy) * 64 + gx;
#pragma unroll
                        for (int j = 0; j < 8; ++j) xv[i][j] = xp[(size_t)j * 4096];
                    }
                }
            }
        }

        // ---- compute phase p ----
        int xr0 = wc * 2 + dy;
#pragma unroll
        for (int dx = 0; dx < 3; ++dx) {
            s16x8 a[4];
#pragma unroll
            for (int mt = 0; mt < 4; ++mt)
                a[mt] = *(const s16x8*)&wcur[(size_t)(dx * 128 + wr * 64 + mt * 16 + l15) * 40 + g * 8];
#pragma unroll
            for (int rr = 0; rr < 2; ++rr) {
#pragma unroll
                for (int nt = 0; nt < 4; ++nt) {
                    s16x8 bf = *(const s16x8*)&xs[(size_t)((xr0 + rr) * 66 + nt * 16 + l15 + dx) * 40 + g * 8];
#pragma unroll
                    for (int mt = 0; mt < 4; ++mt)
                        acc[rr][mt][nt] = __builtin_amdgcn_mfma_f32_16x16x32_bf16(
                            a[mt], bf, acc[rr][mt][nt], 0, 0, 0);
                }
            }
        }

        __syncthreads();   // implicit vmcnt(0)+lgkmcnt(0): next wl staged, reads done

        if (p < 11 && dy == 2) {
            // ---- write prefetched x(cc+1) into xs ----
#pragma unroll
            for (int i = 0; i < 5; ++i) {
                int it = w + i * 8;
                int row = it >> 2, colhi = it & 3;
                int gx = colhi * 16 + l15;
                unsigned pk[4];
#pragma unroll
                for (int j = 0; j < 4; ++j)
                    pk[j] = (unsigned)f2bf(xv[i][2 * j]) | ((unsigned)f2bf(xv[i][2 * j + 1]) << 16);
                *(u32x4*)&xs[(size_t)(row * 66 + gx + 1) * 40 + g * 8] = *(const u32x4*)pk;
            }
            __syncthreads();
        }
    }

    // ---- epilogue ----
    int gy0 = y0 + wc * 2;
#pragma unroll
    for (int rr = 0; rr < 2; ++rr)
#pragma unroll
        for (int mt = 0; mt < 4; ++mt)
#pragma unroll
            for (int nt = 0; nt < 4; ++nt) {
                int gx_out = nt * 16 + l15;
#pragma unroll
                for (int j = 0; j < 4; ++j) {
                    int co = wr * 64 + mt * 16 + g * 4 + j;
                    out[(((size_t)b * CCH + co) * 64 + (gy0 + rr)) * 64 + gx_out] = acc[rr][mt][nt][j];
                }
            }
}

extern "C" void kernel_launch(void* const* d_in, const int* in_sizes, int n_in,
                              void* d_out, int out_size, void* d_ws, size_t ws_size,
                              hipStream_t stream) {
    const float* x       = (const float*)d_in[0];   // [32,128,64,64]
    const float* kernels = (const float*)d_in[1];   // [4,128,128,3,3]
    const float* fc_w    = (const float*)d_in[2];   // [4,128]
    const float* fc_b    = (const float*)d_in[3];   // [4]
    float* out = (float*)d_out;

    float* pooled = (float*)d_ws;                                   // 4096 f
    unsigned short* wmix = (unsigned short*)((char*)d_ws + 32768);  // 11.8 MB bf16

    hipFuncSetAttribute((const void*)conv_kernel,
                        hipFuncAttributeMaxDynamicSharedMemorySize, 114240);

    pool_kernel<<<BSZ * CCH, 256, 0, stream>>>(x, pooled);
    mix_kernel<<<2304, 256, 0, stream>>>(kernels, pooled, fc_w, fc_b, wmix);
    conv_kernel<<<256, 512, 114240, stream>>>(x, wmix, out);
}

// Round 5
// 93.668 us; speedup vs baseline: 1.7223x; 1.0725x over previous
//
#include <hip/hip_runtime.h>
#include <math.h>

typedef __attribute__((ext_vector_type(8))) short s16x8;
typedef __attribute__((ext_vector_type(4))) float f32x4;
typedef __attribute__((ext_vector_type(4))) unsigned int u32x4;

#define CCH 128
#define BSZ 32

// fp32 -> bf16 round-to-nearest-even
static __device__ inline unsigned short f2bf(float f) {
    unsigned u = __float_as_uint(f);
    unsigned r = (u + 0x7FFFu + ((u >> 16) & 1u)) >> 16;
    return (unsigned short)r;
}

// ---------------- Kernel A: global average pool ----------------
__global__ __launch_bounds__(256) void pool_kernel(const float* __restrict__ x,
                                                   float* __restrict__ pooled) {
    int blk = blockIdx.x;                 // b*C + c
    const float4* x4 = (const float4*)(x + (size_t)blk * 4096);
    int t = threadIdx.x;
    float s = 0.f;
#pragma unroll
    for (int j = 0; j < 4; ++j) {
        float4 v = x4[j * 256 + t];
        s += v.x + v.y + v.z + v.w;
    }
#pragma unroll
    for (int off = 32; off; off >>= 1) s += __shfl_xor(s, off, 64);
    __shared__ float red[4];
    if ((t & 63) == 0) red[t >> 6] = s;
    __syncthreads();
    if (t == 0) {
        float tot = red[0] + red[1] + red[2] + red[3];
        pooled[blk] = tot * (1.0f / 4096.0f);
    }
}

// ---------------- Kernel W: coeffs + mix -> bf16 in conv tile layout ----------------
// wmix per b: [p(12)][dx(3)][wr(2)][mt(4)][lane(64)][8 bf16]  (1024 B tiles)
// Lane l of tile (p,dx,wr,mt) holds co = wr*64+mt*16+(l&15), ci = (p/3)*32+(l>>4)*8+e,
// tap (dy=p%3, dx) -- exactly the conv A-fragment, so conv loads are 1024B coalesced.
// Block = (b, cc, cog): stages kernels[k][cog*16..+16][cc*32..+32][9] coalesced into
// LDS (co-stride 289 dwords, conflict-free), then emits 9 tiles (dy,dx).
__global__ __launch_bounds__(256) void mix_kernel(const float* __restrict__ kernels,
                                                  const float* __restrict__ pooled,
                                                  const float* __restrict__ fc_w,
                                                  const float* __restrict__ fc_b,
                                                  unsigned short* __restrict__ wmix) {
    extern __shared__ float klds[];   // 4*16*289 = 18496 floats (73984 B)
    int bid = blockIdx.x;
    int b = bid & 31;                 // XCD = bid%8 = b%8 (matches conv)
    int rest = bid >> 5;              // 0..31
    int cc = rest >> 3, cog = rest & 7;
    int t = threadIdx.x;

    // ---- stage kernels slice (coalesced: 288-float runs) ----
    const int KSTR = CCH * CCH * 9;
    for (int s = t; s < 4 * 16 * 288; s += 256) {
        int k = s / 4608;
        int rem = s - k * 4608;
        int co = rem / 288;
        int i = rem - co * 288;            // ci*9 + r
        float v = kernels[(size_t)k * KSTR + ((size_t)(cog * 16 + co) * CCH + cc * 32) * 9 + i];
        klds[k * 4624 + co * 289 + i] = v;
    }

    // ---- routing coefficients (b uniform per block) ----
    float dot0 = fc_b[0], dot1 = fc_b[1], dot2 = fc_b[2], dot3 = fc_b[3];
    const float4* p4  = (const float4*)(pooled + b * CCH);
    const float4* w40 = (const float4*)(fc_w);
    const float4* w41 = (const float4*)(fc_w + CCH);
    const float4* w42 = (const float4*)(fc_w + 2 * CCH);
    const float4* w43 = (const float4*)(fc_w + 3 * CCH);
#pragma unroll 8
    for (int j = 0; j < 32; ++j) {
        float4 a = p4[j];
        float4 u;
        u = w40[j]; dot0 += a.x * u.x + a.y * u.y + a.z * u.z + a.w * u.w;
        u = w41[j]; dot1 += a.x * u.x + a.y * u.y + a.z * u.z + a.w * u.w;
        u = w42[j]; dot2 += a.x * u.x + a.y * u.y + a.z * u.z + a.w * u.w;
        u = w43[j]; dot3 += a.x * u.x + a.y * u.y + a.z * u.z + a.w * u.w;
    }
    float s0 = 1.0f / (1.0f + expf(-dot0));
    float s1 = 1.0f / (1.0f + expf(-dot1));
    float s2 = 1.0f / (1.0f + expf(-dot2));
    float s3 = 1.0f / (1.0f + expf(-dot3));
    float m = fmaxf(fmaxf(s0, s1), fmaxf(s2, s3));
    float e0 = expf(s0 - m), e1 = expf(s1 - m), e2 = expf(s2 - m), e3 = expf(s3 - m);
    float inv = 1.0f / (e0 + e1 + e2 + e3);
    float cf0 = e0 * inv, cf1 = e1 * inv, cf2 = e2 * inv, cf3 = e3 * inv;

    __syncthreads();

    // ---- emit 9 tiles (dy,dx) of 64 lane-slots, coalesced 16B writes ----
    int wr = cog >> 2, mt = cog & 3;
    for (int s = t; s < 576; s += 256) {
        int lane = s & 63;
        int tj = s >> 6;                 // 0..8
        int dy = tj / 3, dx = tj - dy * 3;
        int col = lane & 15;             // co_local
        int ci8 = (lane >> 4) * 8;
        unsigned short vals[8];
#pragma unroll
        for (int e = 0; e < 8; ++e) {
            int idx = col * 289 + (ci8 + e) * 9 + dy * 3 + dx;
            float v = cf0 * klds[idx]
                    + cf1 * klds[4624 + idx]
                    + cf2 * klds[2 * 4624 + idx]
                    + cf3 * klds[3 * 4624 + idx];
            vals[e] = f2bf(v);
        }
        int p = cc * 3 + dy;
        size_t off = (size_t)b * 147456
                   + ((size_t)((p * 3 + dx) * 2 + wr) * 4 + mt) * 512 + (size_t)lane * 8;
        *(s16x8*)&wmix[off] = *(const s16x8*)vals;
    }
}

// ---------------- Kernel C: MFMA implicit-GEMM dynamic conv ----------------
// grid = 512 (32 b x 16 ytiles of 4 rows), 512 threads (8 waves: wr2 x wc4).
// Per block: 128 co x (4 rows x 64 cols). Weights consumed as registers via
// coalesced 1024B tile loads (L1/L2-hot, XCD-local); LDS holds only xs.
// 2 blocks/CU (31.7KB LDS, <=128 VGPR), 8 barriers/block.
__global__ __launch_bounds__(512, 4) void conv_kernel(const float* __restrict__ x,
                                                      const unsigned short* __restrict__ wmix,
                                                      float* __restrict__ out) {
    __shared__ unsigned short xs[6 * 66 * 40];   // 31680 B

    int bid = blockIdx.x;
    int b = bid & 31, ytile = bid >> 5;          // XCD = b%8
    int y0 = ytile * 4;
    int t = threadIdx.x;
    int l = t & 63, w = t >> 6;
    int wr = w >> 2, wc = w & 3;
    int l15 = l & 15, g = l >> 4;

    const unsigned short* wb = wmix + (size_t)b * 147456;

    // zero halo columns (col 0 and 65), 6 rows, once
    if (t < 240) {
        int row = t / 40;
        int colsel = (t / 20) & 1;
        int cpart = t % 20;
        *(unsigned*)&xs[(row * 66 + colsel * 65) * 40 + cpart * 2] = 0u;
    }

    f32x4 acc[4][4] = {};

    for (int cc = 0; cc < 4; ++cc) {
        __syncthreads();   // prev compute done (first iter: halo writes ordered)
        // ---- stage xs: 6 rows x 64 cols x 32 ci (bf16, ci-contiguous pad-40) ----
#pragma unroll
        for (int i = 0; i < 3; ++i) {
            int slot = w + i * 8;               // 0..23 = row(6) x colhi(4)
            int row = slot >> 2, colhi = slot & 3;
            int gx = colhi * 16 + l15;
            int gy = y0 + row - 1;
            float v[8];
#pragma unroll
            for (int j = 0; j < 8; ++j) v[j] = 0.f;
            if ((unsigned)gy < 64u) {
                const float* xp = x + (((size_t)b * CCH + cc * 32 + g * 8) * 64 + gy) * 64 + gx;
#pragma unroll
                for (int j = 0; j < 8; ++j) v[j] = xp[(size_t)j * 4096];
            }
            unsigned pk[4];
#pragma unroll
            for (int j = 0; j < 4; ++j)
                pk[j] = (unsigned)f2bf(v[2 * j]) | ((unsigned)f2bf(v[2 * j + 1]) << 16);
            *(u32x4*)&xs[(size_t)(row * 66 + gx + 1) * 40 + g * 8] = *(const u32x4*)pk;
        }
        __syncthreads();
        // ---- compute: 3 dy x 3 dx, A from global (coalesced, L1-hot), B from LDS ----
#pragma unroll
        for (int dy = 0; dy < 3; ++dy) {
            int p = cc * 3 + dy;
            int xrow = wc + dy;
#pragma unroll
            for (int dx = 0; dx < 3; ++dx) {
                const unsigned short* wt = wb + ((size_t)((p * 3 + dx) * 2 + wr) * 4) * 512
                                              + (size_t)l * 8;
                s16x8 a[4];
#pragma unroll
                for (int mt = 0; mt < 4; ++mt)
                    a[mt] = *(const s16x8*)(wt + mt * 512);
#pragma unroll
                for (int nt = 0; nt < 4; ++nt) {
                    s16x8 bf = *(const s16x8*)&xs[(size_t)(xrow * 66 + nt * 16 + l15 + dx) * 40 + g * 8];
#pragma unroll
                    for (int mt = 0; mt < 4; ++mt)
                        acc[mt][nt] = __builtin_amdgcn_mfma_f32_16x16x32_bf16(
                            a[mt], bf, acc[mt][nt], 0, 0, 0);
                }
            }
        }
    }

    // ---- epilogue ----
    int gy = y0 + wc;
#pragma unroll
    for (int mt = 0; mt < 4; ++mt)
#pragma unroll
        for (int nt = 0; nt < 4; ++nt) {
            int gxo = nt * 16 + l15;
#pragma unroll
            for (int j = 0; j < 4; ++j) {
                int co = wr * 64 + mt * 16 + g * 4 + j;
                out[(((size_t)b * CCH + co) * 64 + gy) * 64 + gxo] = acc[mt][nt][j];
            }
        }
}

extern "C" void kernel_launch(void* const* d_in, const int* in_sizes, int n_in,
                              void* d_out, int out_size, void* d_ws, size_t ws_size,
                              hipStream_t stream) {
    const float* x       = (const float*)d_in[0];   // [32,128,64,64]
    const float* kernels = (const float*)d_in[1];   // [4,128,128,3,3]
    const float* fc_w    = (const float*)d_in[2];   // [4,128]
    const float* fc_b    = (const float*)d_in[3];   // [4]
    float* out = (float*)d_out;

    float* pooled = (float*)d_ws;                                   // 4096 f
    unsigned short* wmix = (unsigned short*)((char*)d_ws + 32768);  // 9.4 MB bf16

    hipFuncSetAttribute((const void*)mix_kernel,
                        hipFuncAttributeMaxDynamicSharedMemorySize, 73984);

    pool_kernel<<<BSZ * CCH, 256, 0, stream>>>(x, pooled);
    mix_kernel<<<1024, 256, 73984, stream>>>(kernels, pooled, fc_w, fc_b, wmix);
    conv_kernel<<<512, 512, 0, stream>>>(x, wmix, out);
}

// Round 6
// 78.195 us; speedup vs baseline: 2.0631x; 1.1979x over previous
//
#include <hip/hip_runtime.h>
#include <math.h>

typedef __attribute__((ext_vector_type(8))) short s16x8;
typedef __attribute__((ext_vector_type(4))) float f32x4;
typedef __attribute__((ext_vector_type(4))) unsigned int u32x4;

#define CCH 128
#define BSZ 32

// fp32 -> bf16 round-to-nearest-even
static __device__ inline unsigned short f2bf(float f) {
    unsigned u = __float_as_uint(f);
    unsigned r = (u + 0x7FFFu + ((u >> 16) & 1u)) >> 16;
    return (unsigned short)r;
}

// ---------------- Kernel A: global average pool ----------------
__global__ __launch_bounds__(256) void pool_kernel(const float* __restrict__ x,
                                                   float* __restrict__ pooled) {
    int blk = blockIdx.x;                 // b*C + c
    const float4* x4 = (const float4*)(x + (size_t)blk * 4096);
    int t = threadIdx.x;
    float s = 0.f;
#pragma unroll
    for (int j = 0; j < 4; ++j) {
        float4 v = x4[j * 256 + t];
        s += v.x + v.y + v.z + v.w;
    }
#pragma unroll
    for (int off = 32; off; off >>= 1) s += __shfl_xor(s, off, 64);
    __shared__ float red[4];
    if ((t & 63) == 0) red[t >> 6] = s;
    __syncthreads();
    if (t == 0) {
        float tot = red[0] + red[1] + red[2] + red[3];
        pooled[blk] = tot * (1.0f / 4096.0f);
    }
}

// ---------------- Kernel B: routing coefficients (once) ----------------
__global__ __launch_bounds__(128) void coeff_kernel(const float* __restrict__ pooled,
                                                    const float* __restrict__ fc_w,
                                                    const float* __restrict__ fc_b,
                                                    float* __restrict__ coeffs) {
    int t = threadIdx.x;
    int b = t >> 2, k = t & 3;
    const float4* p4 = (const float4*)(pooled + b * CCH);
    const float4* w4 = (const float4*)(fc_w + k * CCH);
    float dot = fc_b[k];
#pragma unroll
    for (int j = 0; j < 32; ++j) {
        float4 a = p4[j], w = w4[j];
        dot += a.x * w.x + a.y * w.y + a.z * w.z + a.w * w.w;
    }
    float s = 1.0f / (1.0f + expf(-dot));
    float m = s;
    m = fmaxf(m, __shfl_xor(m, 1, 64));
    m = fmaxf(m, __shfl_xor(m, 2, 64));
    float e = expf(s - m);
    float sum = e;
    sum += __shfl_xor(sum, 1, 64);
    sum += __shfl_xor(sum, 2, 64);
    coeffs[t] = e / sum;
}

// ---------------- Kernel W: mix -> bf16 in conv tile layout ----------------
// wmix per b: [p(12)][dx(3)][wr(2)][mt(4)][lane(64)][8 bf16]  (1024 B tiles)
// Lane l of tile (p,dx,wr,mt): co = wr*64+mt*16+(l&15), ci = (p/3)*32+(l>>4)*8+e,
// tap (dy=p%3, dx) -- exactly the conv A-fragment (1024B coalesced loads there).
// Block = (cc, cog, bq): stages kernels[k][cog*16..+16][cc*32..+32][9] coalesced
// into LDS (co-stride 289, conflict-free), emits for b = bq and bq+16.
// bid%8 == bq%8 == b%8 for both b's -> XCD matches conv's reader.
__global__ __launch_bounds__(256) void mix_kernel(const float* __restrict__ kernels,
                                                  const float* __restrict__ coeffs,
                                                  unsigned short* __restrict__ wmix) {
    extern __shared__ float klds[];   // 4*4624 = 18496 floats (73984 B)
    int bid = blockIdx.x;
    int bq = bid & 15;
    int rest = bid >> 4;              // 0..31
    int cog = rest & 7, cc = rest >> 3;
    int t = threadIdx.x;

    // ---- stage kernels slice (coalesced: 288-float runs; LDS conflict-free) ----
    const int KSTR = CCH * CCH * 9;
    for (int s = t; s < 4 * 16 * 288; s += 256) {
        int k = s / 4608;
        int rem = s - k * 4608;
        int co = rem / 288;
        int i = rem - co * 288;            // ci*9 + tap
        klds[k * 4624 + co * 289 + i] =
            kernels[(size_t)k * KSTR + ((size_t)(cog * 16 + co) * CCH + cc * 32) * 9 + i];
    }
    __syncthreads();

    int wr = cog >> 2, mt = cog & 3;
#pragma unroll
    for (int jb = 0; jb < 2; ++jb) {
        int b = bq + jb * 16;
        float cf0 = coeffs[b * 4 + 0];
        float cf1 = coeffs[b * 4 + 1];
        float cf2 = coeffs[b * 4 + 2];
        float cf3 = coeffs[b * 4 + 3];
        for (int s = t; s < 576; s += 256) {
            int lane = s & 63;
            int tj = s >> 6;                 // 0..8
            int dy = tj / 3, dx = tj - dy * 3;
            int col = lane & 15;             // co_local
            int ci8 = (lane >> 4) * 8;
            unsigned short vals[8];
#pragma unroll
            for (int e = 0; e < 8; ++e) {
                int idx = col * 289 + (ci8 + e) * 9 + dy * 3 + dx;
                float v = cf0 * klds[idx]
                        + cf1 * klds[4624 + idx]
                        + cf2 * klds[2 * 4624 + idx]
                        + cf3 * klds[3 * 4624 + idx];
                vals[e] = f2bf(v);
            }
            int p = cc * 3 + dy;
            size_t off = (size_t)b * 147456
                       + ((size_t)((p * 3 + dx) * 2 + wr) * 4 + mt) * 512 + (size_t)lane * 8;
            *(s16x8*)&wmix[off] = *(const s16x8*)vals;
        }
    }
}

// ---------------- Kernel C: MFMA implicit-GEMM dynamic conv ----------------
// grid = 512 (32 b x 16 ytiles of 4 rows), 512 threads (8 waves: wr2 x wc4).
// Per block: 128 co x (4 rows x 64 cols). Weights consumed as registers via
// coalesced 1024B tile loads (L1/L2-hot, XCD-local); LDS holds only xs.
__global__ __launch_bounds__(512, 4) void conv_kernel(const float* __restrict__ x,
                                                      const unsigned short* __restrict__ wmix,
                                                      float* __restrict__ out) {
    __shared__ unsigned short xs[6 * 66 * 40];   // 31680 B

    int bid = blockIdx.x;
    int b = bid & 31, ytile = bid >> 5;          // XCD = b%8
    int y0 = ytile * 4;
    int t = threadIdx.x;
    int l = t & 63, w = t >> 6;
    int wr = w >> 2, wc = w & 3;
    int l15 = l & 15, g = l >> 4;

    const unsigned short* wb = wmix + (size_t)b * 147456;

    // zero halo columns (col 0 and 65), 6 rows, once
    if (t < 240) {
        int row = t / 40;
        int colsel = (t / 20) & 1;
        int cpart = t % 20;
        *(unsigned*)&xs[(row * 66 + colsel * 65) * 40 + cpart * 2] = 0u;
    }

    f32x4 acc[4][4] = {};

    for (int cc = 0; cc < 4; ++cc) {
        __syncthreads();   // prev compute done (first iter: halo writes ordered)
        // ---- stage xs: 6 rows x 64 cols x 32 ci (bf16, ci-contiguous pad-40) ----
#pragma unroll
        for (int i = 0; i < 3; ++i) {
            int slot = w + i * 8;               // 0..23 = row(6) x colhi(4)
            int row = slot >> 2, colhi = slot & 3;
            int gx = colhi * 16 + l15;
            int gy = y0 + row - 1;
            float v[8];
#pragma unroll
            for (int j = 0; j < 8; ++j) v[j] = 0.f;
            if ((unsigned)gy < 64u) {
                const float* xp = x + (((size_t)b * CCH + cc * 32 + g * 8) * 64 + gy) * 64 + gx;
#pragma unroll
                for (int j = 0; j < 8; ++j) v[j] = xp[(size_t)j * 4096];
            }
            unsigned pk[4];
#pragma unroll
            for (int j = 0; j < 4; ++j)
                pk[j] = (unsigned)f2bf(v[2 * j]) | ((unsigned)f2bf(v[2 * j + 1]) << 16);
            *(u32x4*)&xs[(size_t)(row * 66 + gx + 1) * 40 + g * 8] = *(const u32x4*)pk;
        }
        __syncthreads();
        // ---- compute: 3 dy x 3 dx, A from global (coalesced, L1-hot), B from LDS ----
#pragma unroll
        for (int dy = 0; dy < 3; ++dy) {
            int p = cc * 3 + dy;
            int xrow = wc + dy;
#pragma unroll
            for (int dx = 0; dx < 3; ++dx) {
                const unsigned short* wt = wb + ((size_t)((p * 3 + dx) * 2 + wr) * 4) * 512
                                              + (size_t)l * 8;
                s16x8 a[4];
#pragma unroll
                for (int mt = 0; mt < 4; ++mt)
                    a[mt] = *(const s16x8*)(wt + mt * 512);
#pragma unroll
                for (int nt = 0; nt < 4; ++nt) {
                    s16x8 bf = *(const s16x8*)&xs[(size_t)(xrow * 66 + nt * 16 + l15 + dx) * 40 + g * 8];
#pragma unroll
                    for (int mt = 0; mt < 4; ++mt)
                        acc[mt][nt] = __builtin_amdgcn_mfma_f32_16x16x32_bf16(
                            a[mt], bf, acc[mt][nt], 0, 0, 0);
                }
            }
        }
    }

    // ---- epilogue ----
    int gy = y0 + wc;
#pragma unroll
    for (int mt = 0; mt < 4; ++mt)
#pragma unroll
        for (int nt = 0; nt < 4; ++nt) {
            int gxo = nt * 16 + l15;
#pragma unroll
            for (int j = 0; j < 4; ++j) {
                int co = wr * 64 + mt * 16 + g * 4 + j;
                out[(((size_t)b * CCH + co) * 64 + gy) * 64 + gxo] = acc[mt][nt][j];
            }
        }
}

extern "C" void kernel_launch(void* const* d_in, const int* in_sizes, int n_in,
                              void* d_out, int out_size, void* d_ws, size_t ws_size,
                              hipStream_t stream) {
    const float* x       = (const float*)d_in[0];   // [32,128,64,64]
    const float* kernels = (const float*)d_in[1];   // [4,128,128,3,3]
    const float* fc_w    = (const float*)d_in[2];   // [4,128]
    const float* fc_b    = (const float*)d_in[3];   // [4]
    float* out = (float*)d_out;

    float* pooled = (float*)d_ws;                                   // 4096 f
    float* coeffs = pooled + BSZ * CCH;                             // 128 f
    unsigned short* wmix = (unsigned short*)((char*)d_ws + 32768);  // 9.4 MB bf16

    hipFuncSetAttribute((const void*)mix_kernel,
                        hipFuncAttributeMaxDynamicSharedMemorySize, 73984);

    pool_kernel<<<BSZ * CCH, 256, 0, stream>>>(x, pooled);
    coeff_kernel<<<1, 128, 0, stream>>>(pooled, fc_w, fc_b, coeffs);
    mix_kernel<<<512, 256, 73984, stream>>>(kernels, coeffs, wmix);
    conv_kernel<<<512, 512, 0, stream>>>(x, wmix, out);
}